// Round 1
// 1225.362 us; speedup vs baseline: 1.1055x; 1.1055x over previous
//
#include <hip/hip_runtime.h>
#include <stdint.h>

#define B_SZ   8192
#define D_IN   19200
#define D1     512
#define D2     256
#define D_PW   128
#define N_PW   25

typedef __attribute__((ext_vector_type(8))) short bf16x8;
typedef __attribute__((ext_vector_type(4))) float f32x4;

#define DEV static __device__ __forceinline__

// fp32 -> bf16 round-to-nearest-even, bit-level (inputs are finite)
DEV unsigned short cvt1(float a) {
  unsigned int u = __builtin_bit_cast(unsigned int, a);
  u += 0x7FFFu + ((u >> 16) & 1u);
  return (unsigned short)(u >> 16);
}
DEV void load_lds16(const void* g, void* l) {
  __builtin_amdgcn_global_load_lds(
      (const __attribute__((address_space(1))) unsigned int*)g,
      (__attribute__((address_space(3))) unsigned int*)l, 16, 0, 0);
}

// ---------------------------------------------------------------------------
// K0: detect int32/int64 layout of drug_indices, bucket-sort samples by pathway
// ---------------------------------------------------------------------------
__global__ __launch_bounds__(256) void sort_kernel(
    const int* __restrict__ di_raw, const int* __restrict__ drug_pw,
    int* __restrict__ perm, int* __restrict__ dsamp, int* __restrict__ offs) {
  __shared__ int cnt[N_PW];
  __shared__ int off_s[N_PW + 1];
  __shared__ int anyodd;
  const int tid = threadIdx.x;
  if (tid < N_PW) cnt[tid] = 0;
  if (tid == 0) anyodd = 0;
  __syncthreads();
  int loc = 0;
  for (int i = tid; i < B_SZ / 2; i += 256) loc |= di_raw[2 * i + 1];
  if (loc) atomicOr(&anyodd, 1);
  __syncthreads();
  const int m64 = (anyodd == 0);
  for (int i = tid; i < B_SZ; i += 256) {
    int d = m64 ? di_raw[2 * i] : di_raw[i];
    dsamp[i] = d;
    atomicAdd(&cnt[drug_pw[d]], 1);
  }
  __syncthreads();
  if (tid == 0) {
    int s = 0;
    for (int p = 0; p < N_PW; p++) { off_s[p] = s; s += cnt[p]; }
    off_s[N_PW] = s;
    for (int p = 0; p <= N_PW; p++) offs[p] = off_s[p];
  }
  __syncthreads();
  if (tid < N_PW) cnt[tid] = off_s[tid];
  __syncthreads();
  for (int i = tid; i < B_SZ; i += 256) {
    int p = drug_pw[dsamp[i]];
    int pos = atomicAdd(&cnt[p], 1);
    perm[pos] = i;
  }
}

// ---------------------------------------------------------------------------
// K1/K2: transpose fp32 [R][C] -> bf16 [C][R]. 64x64 tiles; each block does
// NT tiles along R for per-block ILP.
// ---------------------------------------------------------------------------
template <int NT>
__global__ __launch_bounds__(256) void transpose_cvt(
    const float* __restrict__ in, unsigned short* __restrict__ out, int R, int C) {
  __shared__ float tile[64][65];
  const int c0 = blockIdx.y * 64;
  const int t = threadIdx.x;
#pragma unroll 1
  for (int tt = 0; tt < NT; tt++) {
    int r0 = (blockIdx.x * NT + tt) * 64;
    float4 v[4];
#pragma unroll
    for (int rep = 0; rep < 4; rep++) {
      int idx = t + rep * 256;
      int row = idx >> 4, c4 = idx & 15;
      v[rep] = *(const float4*)(in + (size_t)(r0 + row) * C + c0 + c4 * 4);
    }
#pragma unroll
    for (int rep = 0; rep < 4; rep++) {
      int idx = t + rep * 256;
      int row = idx >> 4, c4 = idx & 15;
      tile[row][c4 * 4 + 0] = v[rep].x; tile[row][c4 * 4 + 1] = v[rep].y;
      tile[row][c4 * 4 + 2] = v[rep].z; tile[row][c4 * 4 + 3] = v[rep].w;
    }
    __syncthreads();
#pragma unroll
    for (int rep = 0; rep < 4; rep++) {
      int idx = t + rep * 256;
      int crow = idx >> 4, q = idx & 15;
      ushort4 o;
      o.x = cvt1(tile[q * 4 + 0][crow]);
      o.y = cvt1(tile[q * 4 + 1][crow]);
      o.z = cvt1(tile[q * 4 + 2][crow]);
      o.w = cvt1(tile[q * 4 + 3][crow]);
      *(ushort4*)(out + (size_t)(c0 + crow) * R + r0 + q * 4) = o;
    }
    __syncthreads();
  }
}

// ---------------------------------------------------------------------------
// K3: GEMM1  h1 = relu(x @ W1 + b1), x fp32 [8192][19200], W1T bf16 [512][19200]
// 64x128 MxN tile, BK=32, 4 waves in 2x2 (wave-tile 32x64), mfma 16x16x32.
// Grid (128, 4) = 512 blocks = 2 blocks/CU.
//
// Pipelined K-loop (T3/T4-lite + T2 swizzle):
//  - double-buffered LDS (As 2x4KB, Bs 2x8KB), ONE barrier per K-step
//  - A(x fp32) prefetched 2 K-steps ahead into regs; cvt+ds_write 1 ahead
//  - B(W1T) staged 1 ahead via global_load_lds into alternate buffer
//  - counted drain: s_waitcnt vmcnt(2) keeps the A-prefetch in flight
//    across the barrier (never vmcnt(0) in the loop). B issues are pinned
//    BEFORE A issues with sched_barrier(0) so vmcnt(2) is order-safe.
//  - XOR swizzle on 16B slots (slot ^= (row>>1)&3): kills the 8-way
//    ds_read_b128 bank conflict of the [row][32]bf16 layout. B uses
//    linear global_load_lds dest + the same involution on the GLOBAL
//    source address and on the read (both-sides rule, m104/m173).
// ---------------------------------------------------------------------------
__global__ __launch_bounds__(256) void gemm1_kernel(
    const float* __restrict__ x, const unsigned short* __restrict__ w1t,
    const float* __restrict__ b1, unsigned short* __restrict__ h1) {
  __shared__ unsigned short As[2][64 * 32];
  __shared__ unsigned short Bs[2][128 * 32];
  const int t = threadIdx.x;
  const int lane = t & 63, wave = t >> 6;
  const int wm = wave & 1, wn = wave >> 1;
  const int l15 = lane & 15, l4 = lane >> 4;
  const int mb = blockIdx.x * 64, nb = blockIdx.y * 128;
  constexpr int NKT = D_IN / 32;  // 600

  // A staging (reg path): thread j = t + rep*256 loads float4 at row j>>3,
  // float4-slot j&7; ds_write goes to the XOR-swizzled 16B slot.
  const float* ab[2];
  int aw_off[2];  // ushort index into As[buf]
#pragma unroll
  for (int rep = 0; rep < 2; rep++) {
    int j = t + rep * 256;
    int row = j >> 3, c4 = j & 7;
    ab[rep] = x + (size_t)(mb + row) * D_IN + c4 * 4;
    int slot = (c4 >> 1) ^ ((row >> 1) & 3);
    aw_off[rep] = row * 32 + slot * 8 + (c4 & 1) * 4;
  }
  // B staging (global_load_lds, linear LDS dest, swizzled global source)
  const unsigned short* bgb[2];
  unsigned short* bld[2][2];  // [buf][rep], wave-uniform base
#pragma unroll
  for (int rep = 0; rep < 2; rep++) {
    int c = t + rep * 256;
    int row = c >> 2, s = c & 3;
    int sg = s ^ ((row >> 1) & 3);
    bgb[rep] = w1t + (size_t)(nb + row) * D_IN + sg * 8;
    int dst = ((t & ~63) + rep * 256) * 8;
    bld[0][rep] = &Bs[0][dst];
    bld[1][rep] = &Bs[1][dst];
  }
  // fragment read offsets (ushort units), same swizzle involution
  const int swz = (l15 >> 1) & 3;
  int ar_off[2], br_off[4];
#pragma unroll
  for (int i = 0; i < 2; i++)
    ar_off[i] = (wm * 32 + i * 16 + l15) * 32 + (l4 ^ swz) * 8;
#pragma unroll
  for (int j = 0; j < 4; j++)
    br_off[j] = (wn * 64 + j * 16 + l15) * 32 + (l4 ^ swz) * 8;

  f32x4 acc[2][4] = {};
  float4 areg0[2], areg1[2];  // static names: no runtime indexing (rule #20)

  // prologue: B(0)->Bs[0]; A(0)->areg0, A(1)->areg1; cvt A(0)->As[0].
  // cvt's compiler wait (vmcnt(2)) also drains B(0), which is older.
#pragma unroll
  for (int rep = 0; rep < 2; rep++) load_lds16(bgb[rep], bld[0][rep]);
  __builtin_amdgcn_sched_barrier(0);
#pragma unroll
  for (int rep = 0; rep < 2; rep++) areg0[rep] = *(const float4*)(ab[rep]);
#pragma unroll
  for (int rep = 0; rep < 2; rep++) areg1[rep] = *(const float4*)(ab[rep] + 32);
  __builtin_amdgcn_sched_barrier(0);
#pragma unroll
  for (int rep = 0; rep < 2; rep++) {
    ushort4 o;
    o.x = cvt1(areg0[rep].x); o.y = cvt1(areg0[rep].y);
    o.z = cvt1(areg0[rep].z); o.w = cvt1(areg0[rep].w);
    *(ushort4*)(&As[0][aw_off[rep]]) = o;
  }
  asm volatile("s_waitcnt lgkmcnt(0)" ::: "memory");
  __builtin_amdgcn_s_barrier();
  __builtin_amdgcn_sched_barrier(0);

  // Body at step KT: read As/Bs[P0]; stage B(KT+1)->Bs[P1] (gload_lds),
  // prefetch A(KT+2)->APRE (regs), cvt ACVT=A(KT+1)->As[P1]; MFMA on P0;
  // drain to vmcnt(2) (= leave only the A prefetch in flight) + barrier.
#define G1_BODY(KT, P0, P1, APRE, ACVT)                                        \
  {                                                                            \
    const int kb = ((KT) + 1 < NKT) ? (KT) + 1 : NKT - 1;                      \
    const int ka = ((KT) + 2 < NKT) ? (KT) + 2 : NKT - 1;                      \
    _Pragma("unroll") for (int rep = 0; rep < 2; rep++)                        \
        load_lds16(bgb[rep] + (size_t)kb * 32, bld[P1][rep]);                  \
    __builtin_amdgcn_sched_barrier(0);                                         \
    _Pragma("unroll") for (int rep = 0; rep < 2; rep++)                        \
        APRE[rep] = *(const float4*)(ab[rep] + (size_t)ka * 32);               \
    __builtin_amdgcn_sched_barrier(0);                                         \
    _Pragma("unroll") for (int rep = 0; rep < 2; rep++) {                      \
      ushort4 o;                                                               \
      o.x = cvt1(ACVT[rep].x); o.y = cvt1(ACVT[rep].y);                        \
      o.z = cvt1(ACVT[rep].z); o.w = cvt1(ACVT[rep].w);                        \
      *(ushort4*)(&As[P1][aw_off[rep]]) = o;                                   \
    }                                                                          \
    bf16x8 a[2], b[4];                                                         \
    _Pragma("unroll") for (int i = 0; i < 2; i++)                              \
        a[i] = *(const bf16x8*)(&As[P0][ar_off[i]]);                           \
    _Pragma("unroll") for (int j = 0; j < 4; j++)                              \
        b[j] = *(const bf16x8*)(&Bs[P0][br_off[j]]);                           \
    _Pragma("unroll") for (int i = 0; i < 2; i++)                              \
        _Pragma("unroll") for (int j = 0; j < 4; j++)                          \
            acc[i][j] = __builtin_amdgcn_mfma_f32_16x16x32_bf16(               \
                a[i], b[j], acc[i][j], 0, 0, 0);                               \
    asm volatile("s_waitcnt vmcnt(2) lgkmcnt(0)" ::: "memory");                \
    __builtin_amdgcn_s_barrier();                                              \
    __builtin_amdgcn_sched_barrier(0);                                         \
  }

  for (int kt = 0; kt < NKT; kt += 2) {
    G1_BODY(kt, 0, 1, areg0, areg1)
    G1_BODY(kt + 1, 1, 0, areg1, areg0)
  }
#undef G1_BODY

  // epilogue: C row = (lane>>4)*4 + reg, col = lane&15
#pragma unroll
  for (int j = 0; j < 4; j++) {
    int col = nb + wn * 64 + j * 16 + l15;
    float bias = b1[col];
#pragma unroll
    for (int i = 0; i < 2; i++) {
      int row0 = mb + wm * 32 + i * 16 + l4 * 4;
#pragma unroll
      for (int r = 0; r < 4; r++) {
        float v = acc[i][j][r] + bias;
        h1[(size_t)(row0 + r) * D1 + col] = cvt1(v > 0.f ? v : 0.f);
      }
    }
  }
}

// ---------------------------------------------------------------------------
// K4: GEMM2  h2 = relu(h1 @ W2 + b2), both operands bf16. Grid (64,2).
// ---------------------------------------------------------------------------
__global__ __launch_bounds__(256) void gemm2_kernel(
    const unsigned short* __restrict__ h1, const unsigned short* __restrict__ w2t,
    const float* __restrict__ b2, unsigned short* __restrict__ h2) {
  __shared__ unsigned short As[128 * 32];
  __shared__ unsigned short Bs[128 * 32];
  const int t = threadIdx.x;
  const int lane = t & 63, wave = t >> 6;
  const int wm = wave & 1, wn = wave >> 1;
  const int l15 = lane & 15, l4 = lane >> 4;
  const int mb = blockIdx.x * 128, nb = blockIdx.y * 128;

  const unsigned short *ag[2], *bg[2];
  unsigned short *al[2], *bl[2];
#pragma unroll
  for (int rep = 0; rep < 2; rep++) {
    int c = t + rep * 256;
    ag[rep] = h1 + (size_t)(mb + (c >> 2)) * D1 + (c & 3) * 8;
    bg[rep] = w2t + (size_t)(nb + (c >> 2)) * D1 + (c & 3) * 8;
    al[rep] = As + ((t & ~63) + rep * 256) * 8;
    bl[rep] = Bs + ((t & ~63) + rep * 256) * 8;
  }
  const bf16x8* ar[4];
  const bf16x8* br[4];
#pragma unroll
  for (int i = 0; i < 4; i++) {
    ar[i] = (const bf16x8*)(As + (wm * 64 + i * 16 + l15) * 32 + l4 * 8);
    br[i] = (const bf16x8*)(Bs + (wn * 64 + i * 16 + l15) * 32 + l4 * 8);
  }
  f32x4 acc[4][4] = {};
  for (int kt = 0; kt < D1 / 32; kt++) {
#pragma unroll
    for (int rep = 0; rep < 2; rep++) {
      load_lds16(ag[rep], al[rep]); ag[rep] += 32;
      load_lds16(bg[rep], bl[rep]); bg[rep] += 32;
    }
    __syncthreads();
    bf16x8 a[4], b[4];
#pragma unroll
    for (int i = 0; i < 4; i++) a[i] = *ar[i];
#pragma unroll
    for (int j = 0; j < 4; j++) b[j] = *br[j];
#pragma unroll
    for (int i = 0; i < 4; i++)
#pragma unroll
      for (int j = 0; j < 4; j++)
        acc[i][j] = __builtin_amdgcn_mfma_f32_16x16x32_bf16(a[i], b[j], acc[i][j], 0, 0, 0);
    __syncthreads();
  }
#pragma unroll
  for (int j = 0; j < 4; j++) {
    int col = nb + wn * 64 + j * 16 + l15;
    float bias = b2[col];
#pragma unroll
    for (int i = 0; i < 4; i++) {
      int row0 = mb + wm * 64 + i * 16 + l4 * 4;
#pragma unroll
      for (int r = 0; r < 4; r++) {
        float v = acc[i][j][r] + bias;
        h2[(size_t)(row0 + r) * D2 + col] = cvt1(v > 0.f ? v : 0.f);
      }
    }
  }
}

// ---------------------------------------------------------------------------
// K5: pathway heads + fused drug dot. Grid (64 chunks, 25 pathways).
// out[b] = relu(h2[b] @ Wp[p]^T + bp[p]) . Wd[d] + bd[d]
// ---------------------------------------------------------------------------
__global__ __launch_bounds__(256) void pathway_kernel(
    const unsigned short* __restrict__ h2, const float* __restrict__ Wp,
    const float* __restrict__ bp, const float* __restrict__ Wd,
    const float* __restrict__ bd, const int* __restrict__ perm,
    const int* __restrict__ dsamp, const int* __restrict__ offs,
    float* __restrict__ out) {
  const int p = blockIdx.y;
  const int start = offs[p];
  const int cnt = offs[p + 1] - start;
  const int r0 = blockIdx.x * 128;
  if (r0 >= cnt) return;

  __shared__ unsigned short As[128 * 32];
  __shared__ unsigned short Bs[128 * 32];
  __shared__ int rowsmp[128];
  __shared__ int dl[128];
  __shared__ float rowacc[128];

  const int t = threadIdx.x;
  const int lane = t & 63, wave = t >> 6;
  const int wm = wave & 1, wn = wave >> 1;
  const int l15 = lane & 15, l4 = lane >> 4;

  if (t < 128) {
    int r = r0 + t;
    int s = perm[start + (r < cnt ? r : 0)];
    rowsmp[t] = s;
    dl[t] = dsamp[s];
    rowacc[t] = 0.f;
  }
  __syncthreads();

  const unsigned short* ag[2];
  unsigned short* al[2];
#pragma unroll
  for (int rep = 0; rep < 2; rep++) {
    int c = t + rep * 256;
    ag[rep] = h2 + (size_t)rowsmp[c >> 2] * D2 + (c & 3) * 8;
    al[rep] = As + ((t & ~63) + rep * 256) * 8;
  }
  const float4* bg[4];
  ushort4* bw[4];
#pragma unroll
  for (int rep = 0; rep < 4; rep++) {
    int j = t + rep * 256;
    bg[rep] = (const float4*)(Wp + ((size_t)p * D_PW + (j >> 3)) * D2 + (j & 7) * 4);
    bw[rep] = (ushort4*)(Bs + j * 4);
  }
  const bf16x8* ar[4];
  const bf16x8* br[4];
#pragma unroll
  for (int i = 0; i < 4; i++) {
    ar[i] = (const bf16x8*)(As + (wm * 64 + i * 16 + l15) * 32 + l4 * 8);
    br[i] = (const bf16x8*)(Bs + (wn * 64 + i * 16 + l15) * 32 + l4 * 8);
  }

  f32x4 acc[4][4] = {};
  for (int kt = 0; kt < D2 / 32; kt++) {
#pragma unroll
    for (int rep = 0; rep < 2; rep++) {
      load_lds16(ag[rep], al[rep]); ag[rep] += 32;
    }
#pragma unroll
    for (int rep = 0; rep < 4; rep++) {
      float4 v = *bg[rep]; bg[rep] += 8;
      ushort4 o;
      o.x = cvt1(v.x); o.y = cvt1(v.y); o.z = cvt1(v.z); o.w = cvt1(v.w);
      *bw[rep] = o;
    }
    __syncthreads();
    bf16x8 a[4], b[4];
#pragma unroll
    for (int i = 0; i < 4; i++) a[i] = *ar[i];
#pragma unroll
    for (int j = 0; j < 4; j++) b[j] = *br[j];
#pragma unroll
    for (int i = 0; i < 4; i++)
#pragma unroll
      for (int j = 0; j < 4; j++)
        acc[i][j] = __builtin_amdgcn_mfma_f32_16x16x32_bf16(a[i], b[j], acc[i][j], 0, 0, 0);
    __syncthreads();
  }

  float p16[4][4];
#pragma unroll
  for (int i = 0; i < 4; i++)
#pragma unroll
    for (int r = 0; r < 4; r++) p16[i][r] = 0.f;

#pragma unroll
  for (int j = 0; j < 4; j++) {
    int col = wn * 64 + j * 16 + l15;
    float bias = bp[p * D_PW + col];
#pragma unroll
    for (int i = 0; i < 4; i++) {
      int rowl0 = wm * 64 + i * 16 + l4 * 4;
#pragma unroll
      for (int r = 0; r < 4; r++) {
        float v = acc[i][j][r] + bias;
        v = v > 0.f ? v : 0.f;
        p16[i][r] += v * Wd[(size_t)dl[rowl0 + r] * D_PW + col];
      }
    }
  }
#pragma unroll
  for (int off = 1; off < 16; off <<= 1) {
#pragma unroll
    for (int i = 0; i < 4; i++)
#pragma unroll
      for (int r = 0; r < 4; r++)
        p16[i][r] += __shfl_xor(p16[i][r], off, 16);
  }
  if (l15 == 0) {
#pragma unroll
    for (int i = 0; i < 4; i++)
#pragma unroll
      for (int r = 0; r < 4; r++)
        atomicAdd(&rowacc[wm * 64 + i * 16 + l4 * 4 + r], p16[i][r]);
  }
  __syncthreads();
  if (t < 128 && r0 + t < cnt) {
    out[rowsmp[t]] = rowacc[t] + bd[dl[t]];
  }
}

// ---------------------------------------------------------------------------
extern "C" void kernel_launch(void* const* d_in, const int* in_sizes, int n_in,
                              void* d_out, int out_size, void* d_ws, size_t ws_size,
                              hipStream_t stream) {
  const float* x       = (const float*)d_in[0];
  const float* W1      = (const float*)d_in[1];
  const float* b1      = (const float*)d_in[2];
  const float* W2      = (const float*)d_in[3];
  const float* b2      = (const float*)d_in[4];
  const float* Wp      = (const float*)d_in[5];
  const float* bp      = (const float*)d_in[6];
  const float* Wd      = (const float*)d_in[7];
  const float* bd      = (const float*)d_in[8];
  const int*   di_raw  = (const int*)d_in[9];
  const int*   drug_pw = (const int*)d_in[10];
  float* out = (float*)d_out;

  char* ws = (char*)d_ws;
  size_t o = 0;
  unsigned short* W1T = (unsigned short*)(ws + o); o += (size_t)D1 * D_IN * 2;
  unsigned short* W2T = (unsigned short*)(ws + o); o += (size_t)D2 * D1 * 2;
  unsigned short* h1  = (unsigned short*)(ws + o); o += (size_t)B_SZ * D1 * 2;
  unsigned short* h2  = (unsigned short*)(ws + o); o += (size_t)B_SZ * D2 * 2;
  int* perm  = (int*)(ws + o); o += (size_t)B_SZ * 4;
  int* dsamp = (int*)(ws + o); o += (size_t)B_SZ * 4;
  int* offs  = (int*)(ws + o); o += 128;
  (void)in_sizes; (void)n_in; (void)out_size; (void)ws_size;

  sort_kernel<<<1, 256, 0, stream>>>(di_raw, drug_pw, perm, dsamp, offs);
  transpose_cvt<4><<<dim3(D_IN / 256, D1 / 64), 256, 0, stream>>>(W1, W1T, D_IN, D1);
  transpose_cvt<1><<<dim3(D1 / 64, D2 / 64), 256, 0, stream>>>(W2, W2T, D1, D2);
  gemm1_kernel<<<dim3(B_SZ / 64, D1 / 128), 256, 0, stream>>>(x, W1T, b1, h1);
  gemm2_kernel<<<dim3(B_SZ / 128, D2 / 128), 256, 0, stream>>>(h1, W2T, b2, h2);
  pathway_kernel<<<dim3(64, N_PW), 256, 0, stream>>>(h2, Wp, bp, Wd, bd,
                                                     perm, dsamp, offs, out);
}